// Round 1
// baseline (778.672 us; speedup 1.0000x reference)
//
#include <hip/hip_runtime.h>

typedef __attribute__((ext_vector_type(8))) short bf16x8;
typedef __attribute__((ext_vector_type(4))) float f32x4;

#define NN 50000
#define HH 128

static __device__ __forceinline__ unsigned short f2bf(float f) {
  unsigned u = __builtin_bit_cast(unsigned, f);
  u = u + 0x7FFFu + ((u >> 16) & 1u);
  return (unsigned short)(u >> 16);
}

static __device__ __forceinline__ bf16x8 bfrag(const unsigned short* __restrict__ w,
                                               int kt, int nt, int lane) {
  return *reinterpret_cast<const bf16x8*>(w + (((kt * 8 + nt) * 64 + lane) << 3));
}

// Convert fp32 row-major W[K][128] into bf16 MFMA B-fragment layout:
// out[((kt*8+nt)*64+lane)*8+j] = bf16(W[kt*32+(lane>>4)*8+j][nt*16+(lane&15)])
__global__ void swz_kernel(const float* __restrict__ W, unsigned short* __restrict__ out,
                           int total) {
  int o = blockIdx.x * 256 + threadIdx.x;
  if (o >= total) return;
  int j = o & 7, lane = (o >> 3) & 63, nt = (o >> 9) & 7, kt = o >> 12;
  int row = kt * 32 + (lane >> 4) * 8 + j;
  int col = nt * 16 + (lane & 15);
  out[o] = f2bf(W[row * 128 + col]);
}

// Per-scale edge message MLP + scatter-add.
// msg = relu([x[src],x[dst],ea] @ W1 + b1) @ W2 + b2 ; agg[dst] += msg
// K=259 split: x[src]@W1[0:128] + x[dst]@W1[128:256] (MFMA) + ea@W1[256:259] (VALU).
__global__ __launch_bounds__(256) void edge_kernel(
    const float* __restrict__ x, const int* __restrict__ ei, const float* __restrict__ ea,
    const float* __restrict__ W1f, const float* __restrict__ b1, const float* __restrict__ b2,
    const unsigned short* __restrict__ W1a, const unsigned short* __restrict__ W1b,
    const unsigned short* __restrict__ W2, float* __restrict__ agg, int E) {
  __shared__ unsigned short As[64][136];   // x[src] bf16, later reused for h1
  __shared__ unsigned short Ad[64][136];   // x[dst] bf16
  __shared__ float eas[64][4];
  __shared__ int dsts[64];
  const int t = threadIdx.x;
  const int e0 = blockIdx.x * 64;

  // Stage: gather + convert 64 edge rows (float4 loads, ushort4 LDS stores)
  for (int idx = t; idx < 64 * 32; idx += 256) {
    int e = idx >> 5, c4 = (idx & 31) << 2;
    int ge = e0 + e;
    float4 vs = make_float4(0.f, 0.f, 0.f, 0.f);
    float4 vd = vs;
    if (ge < E) {
      int s = ei[ge];
      int d = ei[E + ge];
      vs = *reinterpret_cast<const float4*>(x + (long)s * HH + c4);
      vd = *reinterpret_cast<const float4*>(x + (long)d * HH + c4);
    }
    ushort4 us = make_ushort4(f2bf(vs.x), f2bf(vs.y), f2bf(vs.z), f2bf(vs.w));
    ushort4 ud = make_ushort4(f2bf(vd.x), f2bf(vd.y), f2bf(vd.z), f2bf(vd.w));
    *reinterpret_cast<ushort4*>(&As[e][c4]) = us;
    *reinterpret_cast<ushort4*>(&Ad[e][c4]) = ud;
  }
  if (t < 64) {
    int ge = e0 + t;
    if (ge < E) {
      dsts[t] = ei[E + ge];
      eas[t][0] = ea[(long)ge * 3 + 0];
      eas[t][1] = ea[(long)ge * 3 + 1];
      eas[t][2] = ea[(long)ge * 3 + 2];
    } else {
      dsts[t] = -1;
      eas[t][0] = eas[t][1] = eas[t][2] = 0.f;
    }
  }
  __syncthreads();

  const int wave = t >> 6, lane = t & 63;
  const int lr = lane & 15, lgp = lane >> 4;

  // GEMM1: h = x_src @ W1a + x_dst @ W1b   (each wave owns 16 edge rows)
  f32x4 acc[8];
#pragma unroll
  for (int nt = 0; nt < 8; ++nt) acc[nt] = (f32x4){0.f, 0.f, 0.f, 0.f};
#pragma unroll
  for (int kt = 0; kt < 4; ++kt) {
    bf16x8 a_s = *reinterpret_cast<const bf16x8*>(&As[wave * 16 + lr][kt * 32 + lgp * 8]);
    bf16x8 a_d = *reinterpret_cast<const bf16x8*>(&Ad[wave * 16 + lr][kt * 32 + lgp * 8]);
#pragma unroll
    for (int nt = 0; nt < 8; ++nt) {
      acc[nt] = __builtin_amdgcn_mfma_f32_16x16x32_bf16(a_s, bfrag(W1a, kt, nt, lane), acc[nt], 0, 0, 0);
      acc[nt] = __builtin_amdgcn_mfma_f32_16x16x32_bf16(a_d, bfrag(W1b, kt, nt, lane), acc[nt], 0, 0, 0);
    }
  }

  // Epilogue 1: + b1 + ea rank-3 (fp32), relu, h1 -> LDS (wave-private rows, no barrier)
  // C layout: row = wave*16 + lgp*4 + r, col = nt*16 + lr
#pragma unroll
  for (int nt = 0; nt < 8; ++nt) {
    int col = nt * 16 + lr;
    float wc0 = W1f[256 * HH + col];
    float wc1 = W1f[257 * HH + col];
    float wc2 = W1f[258 * HH + col];
    float bb = b1[col];
#pragma unroll
    for (int r = 0; r < 4; ++r) {
      int row = wave * 16 + lgp * 4 + r;
      float v = acc[nt][r] + bb + eas[row][0] * wc0 + eas[row][1] * wc1 + eas[row][2] * wc2;
      As[row][col] = f2bf(fmaxf(v, 0.f));
    }
  }

  // GEMM2: msg = h1 @ W2
  f32x4 acc2[8];
#pragma unroll
  for (int nt = 0; nt < 8; ++nt) acc2[nt] = (f32x4){0.f, 0.f, 0.f, 0.f};
#pragma unroll
  for (int kt = 0; kt < 4; ++kt) {
    bf16x8 a = *reinterpret_cast<const bf16x8*>(&As[wave * 16 + lr][kt * 32 + lgp * 8]);
#pragma unroll
    for (int nt = 0; nt < 8; ++nt) {
      acc2[nt] = __builtin_amdgcn_mfma_f32_16x16x32_bf16(a, bfrag(W2, kt, nt, lane), acc2[nt], 0, 0, 0);
    }
  }

  // Scatter: agg[dst] += msg + b2
#pragma unroll
  for (int nt = 0; nt < 8; ++nt) {
    int col = nt * 16 + lr;
    float bb = b2[col];
#pragma unroll
    for (int r = 0; r < 4; ++r) {
      int row = wave * 16 + lgp * 4 + r;
      int d = dsts[row];
      if (d >= 0) atomicAdd(agg + (long)d * HH + col, acc2[nt][r] + bb);
    }
  }
}

// Node update: u=[x,la,ma,lo]; gate=sigmoid(u@Wg+bg); upd=relu(u@Wu1+bu1)@Wu2+bu2;
// out = LN(gate*upd + (1-gate)*x) * gamma + beta
__global__ __launch_bounds__(256) void node_kernel(
    const float* __restrict__ x, const float* __restrict__ la, const float* __restrict__ ma,
    const float* __restrict__ lo,
    const unsigned short* __restrict__ Wg, const unsigned short* __restrict__ Wu1,
    const unsigned short* __restrict__ Wu2,
    const float* __restrict__ bg, const float* __restrict__ bu1, const float* __restrict__ bu2,
    const float* __restrict__ gamma, const float* __restrict__ beta,
    float* __restrict__ out) {
  __shared__ unsigned short Hs[64][136];
  const int t = threadIdx.x;
  const int n0 = blockIdx.x * 64;
  const int wave = t >> 6, lane = t & 63;
  const int lr = lane & 15, lgp = lane >> 4;

  f32x4 accG[8], accH[8];
#pragma unroll
  for (int nt = 0; nt < 8; ++nt) {
    accG[nt] = (f32x4){0.f, 0.f, 0.f, 0.f};
    accH[nt] = (f32x4){0.f, 0.f, 0.f, 0.f};
  }
  const int arow = n0 + wave * 16 + lr;
  const bool aok = arow < NN;

  // K=512 over [x | la | ma | lo], A-fragments straight from global (contiguous rows)
#pragma unroll
  for (int kt = 0; kt < 16; ++kt) {
    const float* S = (kt < 4) ? x : (kt < 8) ? la : (kt < 12) ? ma : lo;
    int cb = ((kt & 3) << 5) + (lgp << 3);
    bf16x8 a;
    if (aok) {
      float4 f0 = *reinterpret_cast<const float4*>(S + (long)arow * HH + cb);
      float4 f1 = *reinterpret_cast<const float4*>(S + (long)arow * HH + cb + 4);
      a[0] = (short)f2bf(f0.x); a[1] = (short)f2bf(f0.y);
      a[2] = (short)f2bf(f0.z); a[3] = (short)f2bf(f0.w);
      a[4] = (short)f2bf(f1.x); a[5] = (short)f2bf(f1.y);
      a[6] = (short)f2bf(f1.z); a[7] = (short)f2bf(f1.w);
    } else {
      a = (bf16x8){0, 0, 0, 0, 0, 0, 0, 0};
    }
#pragma unroll
    for (int nt = 0; nt < 8; ++nt) {
      accG[nt] = __builtin_amdgcn_mfma_f32_16x16x32_bf16(a, bfrag(Wg, kt, nt, lane), accG[nt], 0, 0, 0);
      accH[nt] = __builtin_amdgcn_mfma_f32_16x16x32_bf16(a, bfrag(Wu1, kt, nt, lane), accH[nt], 0, 0, 0);
    }
  }

  // gate = sigmoid(accG+bg) kept in regs; h1 = relu(accH+bu1) -> LDS bf16
#pragma unroll
  for (int nt = 0; nt < 8; ++nt) {
    int col = nt * 16 + lr;
    float bgv = bg[col], bhv = bu1[col];
#pragma unroll
    for (int r = 0; r < 4; ++r) {
      float g = 1.f / (1.f + __expf(-(accG[nt][r] + bgv)));
      accG[nt][r] = g;
      float h = fmaxf(accH[nt][r] + bhv, 0.f);
      Hs[wave * 16 + lgp * 4 + r][col] = f2bf(h);
    }
  }

  // GEMM2: upd = h1 @ Wu2
  f32x4 accU[8];
#pragma unroll
  for (int nt = 0; nt < 8; ++nt) accU[nt] = (f32x4){0.f, 0.f, 0.f, 0.f};
#pragma unroll
  for (int kt = 0; kt < 4; ++kt) {
    bf16x8 a = *reinterpret_cast<const bf16x8*>(&Hs[wave * 16 + lr][kt * 32 + lgp * 8]);
#pragma unroll
    for (int nt = 0; nt < 8; ++nt) {
      accU[nt] = __builtin_amdgcn_mfma_f32_16x16x32_bf16(a, bfrag(Wu2, kt, nt, lane), accU[nt], 0, 0, 0);
    }
  }

  // combine: v = gate*upd + (1-gate)*x   (store v back into accU)
#pragma unroll
  for (int nt = 0; nt < 8; ++nt) {
    int col = nt * 16 + lr;
    float b2v = bu2[col];
#pragma unroll
    for (int r = 0; r < 4; ++r) {
      int row = n0 + wave * 16 + lgp * 4 + r;
      float xv = (row < NN) ? x[(long)row * HH + col] : 0.f;
      float u = accU[nt][r] + b2v;
      float g = accG[nt][r];
      accU[nt][r] = g * u + (1.f - g) * xv;
    }
  }

  // LayerNorm per row (16 lanes share a row-group; reduce via shfl_xor 1,2,4,8)
#pragma unroll
  for (int r = 0; r < 4; ++r) {
    int row = n0 + wave * 16 + lgp * 4 + r;
    float s = 0.f;
#pragma unroll
    for (int nt = 0; nt < 8; ++nt) s += accU[nt][r];
    s += __shfl_xor(s, 1, 64);
    s += __shfl_xor(s, 2, 64);
    s += __shfl_xor(s, 4, 64);
    s += __shfl_xor(s, 8, 64);
    float mu = s * (1.f / 128.f);
    float q = 0.f;
#pragma unroll
    for (int nt = 0; nt < 8; ++nt) {
      float d = accU[nt][r] - mu;
      q += d * d;
    }
    q += __shfl_xor(q, 1, 64);
    q += __shfl_xor(q, 2, 64);
    q += __shfl_xor(q, 4, 64);
    q += __shfl_xor(q, 8, 64);
    float rs = rsqrtf(q * (1.f / 128.f) + 1e-5f);
    if (row < NN) {
#pragma unroll
      for (int nt = 0; nt < 8; ++nt) {
        int col = nt * 16 + lr;
        out[(long)row * HH + col] = (accU[nt][r] - mu) * rs * gamma[col] + beta[col];
      }
    }
  }
}

extern "C" void kernel_launch(void* const* d_in, const int* in_sizes, int n_in,
                              void* d_out, int out_size, void* d_ws, size_t ws_size,
                              hipStream_t stream) {
  const float* x = (const float*)d_in[0];
  const int* ei_l = (const int*)d_in[1];
  const float* ea_l = (const float*)d_in[2];
  const int* ei_m = (const int*)d_in[3];
  const float* ea_m = (const float*)d_in[4];
  const int* ei_g = (const int*)d_in[5];
  const float* ea_g = (const float*)d_in[6];
  const float* Wa1 = (const float*)d_in[7];
  const float* ba1 = (const float*)d_in[8];
  const float* Wa2 = (const float*)d_in[9];
  const float* ba2 = (const float*)d_in[10];
  const float* Wb1 = (const float*)d_in[11];
  const float* bb1 = (const float*)d_in[12];
  const float* Wb2 = (const float*)d_in[13];
  const float* bb2 = (const float*)d_in[14];
  const float* Wc1 = (const float*)d_in[15];
  const float* bc1 = (const float*)d_in[16];
  const float* Wc2 = (const float*)d_in[17];
  const float* bc2 = (const float*)d_in[18];
  const float* Wg = (const float*)d_in[19];
  const float* bg = (const float*)d_in[20];
  const float* Wu1 = (const float*)d_in[21];
  const float* bu1 = (const float*)d_in[22];
  const float* Wu2 = (const float*)d_in[23];
  const float* bu2 = (const float*)d_in[24];
  const float* gamma = (const float*)d_in[25];
  const float* beta = (const float*)d_in[26];

  const int El = in_sizes[1] / 2;
  const int Em = in_sizes[3] / 2;
  const int Eg = in_sizes[5] / 2;

  // Workspace layout
  float* la = (float*)d_ws;                 // N*H
  float* ma = la + (size_t)NN * HH;         // N*H
  float* lo = ma + (size_t)NN * HH;         // N*H
  unsigned short* wp = (unsigned short*)(lo + (size_t)NN * HH);
  unsigned short* W1a_a = wp; wp += 128 * 128;
  unsigned short* W1b_a = wp; wp += 128 * 128;
  unsigned short* W2_a  = wp; wp += 128 * 128;
  unsigned short* W1a_b = wp; wp += 128 * 128;
  unsigned short* W1b_b = wp; wp += 128 * 128;
  unsigned short* W2_b  = wp; wp += 128 * 128;
  unsigned short* W1a_c = wp; wp += 128 * 128;
  unsigned short* W1b_c = wp; wp += 128 * 128;
  unsigned short* W2_c  = wp; wp += 128 * 128;
  unsigned short* Wg_s  = wp; wp += 512 * 128;
  unsigned short* Wu1_s = wp; wp += 512 * 128;
  unsigned short* Wu2_s = wp; wp += 128 * 128;

  // Zero the three aggregation buffers
  hipMemsetAsync(d_ws, 0, (size_t)3 * NN * HH * sizeof(float), stream);

  // Weight swizzle pre-passes (bf16 B-fragment layout)
  auto swz = [&](const float* W, unsigned short* o, int K) {
    int total = K * 128;
    swz_kernel<<<(total + 255) / 256, 256, 0, stream>>>(W, o, total);
  };
  swz(Wa1, W1a_a, 128); swz(Wa1 + 128 * 128, W1b_a, 128); swz(Wa2, W2_a, 128);
  swz(Wb1, W1a_b, 128); swz(Wb1 + 128 * 128, W1b_b, 128); swz(Wb2, W2_b, 128);
  swz(Wc1, W1a_c, 128); swz(Wc1 + 128 * 128, W1b_c, 128); swz(Wc2, W2_c, 128);
  swz(Wg, Wg_s, 512);   swz(Wu1, Wu1_s, 512);             swz(Wu2, Wu2_s, 128);

  // Edge message passes
  edge_kernel<<<(El + 63) / 64, 256, 0, stream>>>(x, ei_l, ea_l, Wa1, ba1, ba2,
                                                  W1a_a, W1b_a, W2_a, la, El);
  edge_kernel<<<(Em + 63) / 64, 256, 0, stream>>>(x, ei_m, ea_m, Wb1, bb1, bb2,
                                                  W1a_b, W1b_b, W2_b, ma, Em);
  edge_kernel<<<(Eg + 63) / 64, 256, 0, stream>>>(x, ei_g, ea_g, Wc1, bc1, bc2,
                                                  W1a_c, W1b_c, W2_c, lo, Eg);

  // Node update + LayerNorm
  node_kernel<<<(NN + 63) / 64, 256, 0, stream>>>(x, la, ma, lo, Wg_s, Wu1_s, Wu2_s,
                                                  bg, bu1, bu2, gamma, beta, (float*)d_out);
}